// Round 9
// baseline (1070.024 us; speedup 1.0000x reference)
//
#include <hip/hip_runtime.h>
#include <hip/hip_bf16.h>

#define RFn 500000
#define F1n 256
#define NFn 128
#define RAn 50000
#define LN_EPSn 1e-5f
#define SPW 5                          // segments per wave (fused kernel)
#define NWV ((RAn + SPW - 1) / SPW)    // 10000 waves
#define NBLK2 ((NWV + 7) / 8)          // 1250 blocks of 8 waves
#define SCB 256
#define SCG ((RAn + SCB - 1) / SCB)    // 196

typedef float f32x4 __attribute__((ext_vector_type(4)));
typedef short short8 __attribute__((ext_vector_type(8)));

__device__ __forceinline__ short f2bf(float f) {
  __hip_bfloat16 h = __float2bfloat16(f);  // RNE
  return __builtin_bit_cast(short, h);
}

// ---------------------------------------------------------------------------
// Pack W_feat (256x128 f32) into MFMA B-frag image: frag (s,c), lane l:
// col = c*16+(l&15), k = s*32+(l>>4)*8+i  (8 bf16 per lane).
// ---------------------------------------------------------------------------
__global__ void prep_kernel(const float* __restrict__ Wf, short* __restrict__ frag) {
  int p = blockIdx.x * blockDim.x + threadIdx.x;  // 0..4095
  if (p >= 4096) return;
  int f = p >> 6, l = p & 63;
  int s = f >> 3, c = f & 7;
  int col = c * 16 + (l & 15);
  int k0 = s * 32 + ((l >> 4) << 3);
  short8 v;
#pragma unroll
  for (int i = 0; i < 8; ++i) v[i] = f2bf(Wf[(k0 + i) * NFn + col]);
  *(short8*)(frag + (size_t)p * 8) = v;
}

__global__ void hist_kernel(const int* __restrict__ ri, int* __restrict__ hist) {
  int i = blockIdx.x * 256 + threadIdx.x;
  if (i < RFn) atomicAdd(&hist[ri[i]], 1);
}

__global__ __launch_bounds__(256) void scanA_kernel(const int* __restrict__ hist,
                                                    int* __restrict__ T,
                                                    int* __restrict__ bsum) {
  __shared__ int ls[256];
  const int t = threadIdx.x, idx = blockIdx.x * 256 + t;
  const int v = (idx < RAn) ? hist[idx] : 0;
  ls[t] = v;
  __syncthreads();
  for (int off = 1; off < 256; off <<= 1) {
    int add = (t >= off) ? ls[t - off] : 0;
    __syncthreads();
    ls[t] += add;
    __syncthreads();
  }
  if (idx < RAn) T[idx] = ls[t] - v;
  if (t == 255) bsum[blockIdx.x] = ls[255];
}

__global__ __launch_bounds__(256) void scanB_kernel(int* __restrict__ bsum,
                                                    int* __restrict__ boff) {
  __shared__ int ls[256];
  const int t = threadIdx.x;
  const int v = (t < SCG) ? bsum[t] : 0;
  ls[t] = v;
  __syncthreads();
  for (int off = 1; off < 256; off <<= 1) {
    int add = (t >= off) ? ls[t - off] : 0;
    __syncthreads();
    ls[t] += add;
    __syncthreads();
  }
  if (t < SCG) boff[t] = ls[t] - v;
}

__global__ __launch_bounds__(256) void scanC_kernel(const int* __restrict__ T,
                                                    const int* __restrict__ boff,
                                                    int* __restrict__ rowstart,
                                                    int* __restrict__ cursor) {
  const int idx = blockIdx.x * 256 + threadIdx.x;
  if (idx < RAn) {
    int v = T[idx] + boff[blockIdx.x];
    rowstart[idx] = v;
    cursor[idx] = v;
  }
  if (idx == 0) rowstart[RAn] = RFn;
}

// perm[pos] = original row; sseg[pos] = its segment (segment-major order)
__global__ void scatter_kernel(const int* __restrict__ ri, int* __restrict__ cursor,
                               int* __restrict__ perm, int* __restrict__ sseg) {
  int i = blockIdx.x * 256 + threadIdx.x;
  if (i < RFn) {
    int s = ri[i];
    int pos = atomicAdd(&cursor[s], 1);
    perm[pos] = i;
    sseg[pos] = s;
  }
}

// ---------------------------------------------------------------------------
// fused: single pass. 512-thr blocks (8 waves) share the 64KB B-frag image +
// 1.5KB coef table in LDS; each wave owns SPW consecutive segments (a
// contiguous range of sorted rows). Per 16-row tile: gather rows via perm,
// MFMA GEMM + in-register LN + logit/exp, then in-register segmented
// accumulation. ALL register arrays statically indexed (rule #20): flushes
// use predicated static loops, not racc[2*kg].
// ---------------------------------------------------------------------------
__global__ __launch_bounds__(512, 4) void fused_kernel(
    const float* __restrict__ X, const short* __restrict__ fragWS,
    const float* __restrict__ Wa, const float* __restrict__ ba,
    const float* __restrict__ bfeat, const float* __restrict__ gamma,
    const float* __restrict__ beta, const int* __restrict__ rowstart,
    const int* __restrict__ perm, const int* __restrict__ sseg,
    float* __restrict__ out) {
  __shared__ short sB[4096 * 8];  // 64KB
  __shared__ float sCoef[384];    // gamma[0:128] beta[128:256] bfeat[256:384]

  const int tid = threadIdx.x;
  {
    const int4* src = (const int4*)fragWS;
    int4* dst = (int4*)sB;
#pragma unroll 8
    for (int i = tid; i < 4096; i += 512) dst[i] = src[i];
    if (tid < 128) {
      sCoef[tid] = gamma[tid];
      sCoef[128 + tid] = beta[tid];
      sCoef[256 + tid] = bfeat[tid];
    }
  }
  __syncthreads();

  const int lane = tid & 63;
  const int wv = tid >> 6;
  const int colb = lane & 15;
  const int kg = lane >> 4;

  const int wgid = blockIdx.x * 8 + wv;
  const int s0 = wgid * SPW;
  if (s0 >= RAn) return;
  const int s1 = min(s0 + SPW, RAn);
  const int rbeg = rowstart[s0];
  const int rend = rowstart[s1];
  if (rend <= rbeg) return;  // all empty: out stays 0 (memset)

  const float batn = ba[0];

  // running segment state (identical on all lanes; racc[c] = col c*16+colb)
  float racc[8] = {0.f, 0.f, 0.f, 0.f, 0.f, 0.f, 0.f, 0.f};
  float wrun = 0.f;
  int curseg = -1;

  for (int base = rbeg; base < rend; base += 16) {
    const int n = min(16, rend - base);
    const int pc = base + ((colb < n) ? colb : (n - 1));
    const int row = perm[pc];
    const int seg = sseg[pc];
    const float* xp = X + (size_t)row * F1n + kg * 8;

    // -------- GEMM over K=256 --------
    f32x4 acc[8];
#pragma unroll
    for (int c = 0; c < 8; ++c) acc[c] = (f32x4)(0.0f);
    float logit = 0.f;

#pragma unroll
    for (int s = 0; s < 8; ++s) {
      short8 bfr[8];
#pragma unroll
      for (int c = 0; c < 8; ++c)
        bfr[c] = *(const short8*)(sB + (((s * 8 + c) * 64 + lane) * 8));
      const float4 wa0 = *(const float4*)(Wa + s * 32 + kg * 8);
      const float4 wa1 = *(const float4*)(Wa + s * 32 + kg * 8 + 4);
      const float4 x0 = *(const float4*)(xp + s * 32);
      const float4 x1 = *(const float4*)(xp + s * 32 + 4);
      float a0 = fmaxf(x0.x, 0.01f * x0.x);
      float a1 = fmaxf(x0.y, 0.01f * x0.y);
      float a2 = fmaxf(x0.z, 0.01f * x0.z);
      float a3 = fmaxf(x0.w, 0.01f * x0.w);
      float a4 = fmaxf(x1.x, 0.01f * x1.x);
      float a5 = fmaxf(x1.y, 0.01f * x1.y);
      float a6 = fmaxf(x1.z, 0.01f * x1.z);
      float a7 = fmaxf(x1.w, 0.01f * x1.w);
      logit += a0 * wa0.x + a1 * wa0.y + a2 * wa0.z + a3 * wa0.w +
               a4 * wa1.x + a5 * wa1.y + a6 * wa1.z + a7 * wa1.w;
      short8 af;
      af[0] = f2bf(a0); af[1] = f2bf(a1); af[2] = f2bf(a2); af[3] = f2bf(a3);
      af[4] = f2bf(a4); af[5] = f2bf(a5); af[6] = f2bf(a6); af[7] = f2bf(a7);
#pragma unroll
      for (int c = 0; c < 8; ++c)
        acc[c] = __builtin_amdgcn_mfma_f32_16x16x32_bf16(af, bfr[c], acc[c], 0, 0, 0);
    }

    // -------- logit -> w; LN; feat*w (in place in acc) --------
    float lg = logit;
    lg += __shfl_xor(lg, 16);
    lg += __shfl_xor(lg, 32);
    const float wexp = __expf(lg + batn);

    float w4[4];
#pragma unroll
    for (int reg = 0; reg < 4; ++reg) w4[reg] = __shfl(wexp, kg * 4 + reg);

    float s1v[4] = {0.f, 0.f, 0.f, 0.f}, s2v[4] = {0.f, 0.f, 0.f, 0.f};
#pragma unroll
    for (int c = 0; c < 8; ++c) {
      const float bi = sCoef[256 + c * 16 + colb];
#pragma unroll
      for (int reg = 0; reg < 4; ++reg) {
        float v = acc[c][reg] + bi;
        acc[c][reg] = v;
        s1v[reg] += v;
        s2v[reg] += v * v;
      }
    }
#pragma unroll
    for (int off = 1; off <= 8; off <<= 1)
#pragma unroll
      for (int reg = 0; reg < 4; ++reg) {
        s1v[reg] += __shfl_xor(s1v[reg], off);
        s2v[reg] += __shfl_xor(s2v[reg], off);
      }
    float mu[4], rs[4];
#pragma unroll
    for (int reg = 0; reg < 4; ++reg) {
      mu[reg] = s1v[reg] * (1.0f / NFn);
      const float var = s2v[reg] * (1.0f / NFn) - mu[reg] * mu[reg];
      rs[reg] = rsqrtf(var + LN_EPSn);
    }
#pragma unroll
    for (int c = 0; c < 8; ++c) {
      const float gg = sCoef[c * 16 + colb];
      const float bb = sCoef[128 + c * 16 + colb];
#pragma unroll
      for (int reg = 0; reg < 4; ++reg)
        acc[c][reg] = ((acc[c][reg] - mu[reg]) * rs[reg] * gg + bb) * w4[reg];
    }

    // -------- segmented accumulation over the n rows of this tile --------
    const int lm1 = (lane & 15) ? lane - 1 : lane;  // lane-1 within colb group
    const int segp = __shfl(seg, lm1 & 63);
    unsigned long long bm =
        __ballot(lane < n && ((lane & 15) == 0 || seg != segp));
    bm &= 0xFFFFull;

    int a = 0;
    while (a < n) {
      unsigned long long rest = (a + 1 < 16) ? (bm >> (a + 1)) : 0ull;
      const int b = rest ? (a + 1 + (int)__builtin_ctzll(rest)) : n;
      const int rseg = __shfl(seg, a);

      float ctr[8];
#pragma unroll
      for (int c = 0; c < 8; ++c) ctr[c] = 0.f;
      float wc = 0.f;
#pragma unroll
      for (int reg = 0; reg < 4; ++reg) {
        const int r = kg * 4 + reg;
        if (r >= a && r < b) {
          wc += w4[reg];
#pragma unroll
          for (int c = 0; c < 8; ++c) ctr[c] += acc[c][reg];
        }
      }
#pragma unroll
      for (int c = 0; c < 8; ++c) {
        ctr[c] += __shfl_xor(ctr[c], 16);
        ctr[c] += __shfl_xor(ctr[c], 32);
      }
      wc += __shfl_xor(wc, 16);
      wc += __shfl_xor(wc, 32);

      if (rseg != curseg) {
        if (curseg >= 0) {
          const float iw = 1.0f / wrun;
#pragma unroll
          for (int c = 0; c < 8; ++c)  // static index, predicated (rule #20)
            if ((c >> 1) == kg)
              out[(size_t)curseg * NFn + c * 16 + colb] = racc[c] * iw;
        }
        curseg = rseg;
#pragma unroll
        for (int c = 0; c < 8; ++c) racc[c] = ctr[c];
        wrun = wc;
      } else {
#pragma unroll
        for (int c = 0; c < 8; ++c) racc[c] += ctr[c];
        wrun += wc;
      }
      a = b;
    }
  }

  // final flush
  if (curseg >= 0) {
    const float iw = 1.0f / wrun;
#pragma unroll
    for (int c = 0; c < 8; ++c)  // static index, predicated (rule #20)
      if ((c >> 1) == kg)
        out[(size_t)curseg * NFn + c * 16 + colb] = racc[c] * iw;
  }
}

// ---------------------------------------------------------------------------
// Fallback path (small ws): round-1 atomic kernel, known-good.
// ---------------------------------------------------------------------------
__global__ __launch_bounds__(256) void main_atomic(
    const float* __restrict__ X, const short* __restrict__ fragWS,
    const float* __restrict__ Wa, const float* __restrict__ ba,
    const float* __restrict__ bfeat, const float* __restrict__ gamma,
    const float* __restrict__ beta, const int* __restrict__ res_index,
    float* __restrict__ Nacc, float* __restrict__ D) {
  __shared__ short sB[4096 * 8];
  const int tid = threadIdx.x;
  {
    const int4* src = (const int4*)fragWS;
    int4* dst = (int4*)sB;
#pragma unroll 4
    for (int i = tid; i < 4096; i += 256) dst[i] = src[i];
  }
  __syncthreads();
  const int lane = tid & 63;
  const int wv = tid >> 6;
  const int rowbase = blockIdx.x * 128 + wv * 32;
  const int colb = lane & 15;
  const int kg = lane >> 4;
  float g_r[8], be_r[8], bi_r[8];
#pragma unroll
  for (int c = 0; c < 8; ++c) {
    int col = c * 16 + colb;
    g_r[c] = gamma[col];
    be_r[c] = beta[col];
    bi_r[c] = bfeat[col];
  }
  const float batn = ba[0];
  f32x4 acc[2][8];
#pragma unroll
  for (int rt = 0; rt < 2; ++rt)
#pragma unroll
    for (int c = 0; c < 8; ++c) acc[rt][c] = (f32x4)(0.0f);
  float logit[2] = {0.f, 0.f};
  int gr0 = rowbase + colb;
  int gr1 = gr0 + 16;
  long r0 = (gr0 < RFn) ? gr0 : (RFn - 1);
  long r1 = (gr1 < RFn) ? gr1 : (RFn - 1);
  const float* xp0 = X + r0 * F1n + kg * 8;
  const float* xp1 = X + r1 * F1n + kg * 8;
#pragma unroll
  for (int s = 0; s < 8; ++s) {
    short8 bfr[8];
#pragma unroll
    for (int c = 0; c < 8; ++c)
      bfr[c] = *(const short8*)(sB + (((s * 8 + c) * 64 + lane) * 8));
    const float4 wa0 = *(const float4*)(Wa + s * 32 + kg * 8);
    const float4 wa1 = *(const float4*)(Wa + s * 32 + kg * 8 + 4);
#pragma unroll
    for (int rt = 0; rt < 2; ++rt) {
      const float* xp = rt ? xp1 : xp0;
      const float4 x0 = *(const float4*)(xp + s * 32);
      const float4 x1 = *(const float4*)(xp + s * 32 + 4);
      float a0 = fmaxf(x0.x, 0.01f * x0.x);
      float a1 = fmaxf(x0.y, 0.01f * x0.y);
      float a2 = fmaxf(x0.z, 0.01f * x0.z);
      float a3 = fmaxf(x0.w, 0.01f * x0.w);
      float a4 = fmaxf(x1.x, 0.01f * x1.x);
      float a5 = fmaxf(x1.y, 0.01f * x1.y);
      float a6 = fmaxf(x1.z, 0.01f * x1.z);
      float a7 = fmaxf(x1.w, 0.01f * x1.w);
      logit[rt] += a0 * wa0.x + a1 * wa0.y + a2 * wa0.z + a3 * wa0.w +
                   a4 * wa1.x + a5 * wa1.y + a6 * wa1.z + a7 * wa1.w;
      short8 af;
      af[0] = f2bf(a0); af[1] = f2bf(a1); af[2] = f2bf(a2); af[3] = f2bf(a3);
      af[4] = f2bf(a4); af[5] = f2bf(a5); af[6] = f2bf(a6); af[7] = f2bf(a7);
#pragma unroll
      for (int c = 0; c < 8; ++c)
        acc[rt][c] = __builtin_amdgcn_mfma_f32_16x16x32_bf16(af, bfr[c],
                                                             acc[rt][c], 0, 0, 0);
    }
  }
#pragma unroll
  for (int rt = 0; rt < 2; ++rt) {
    float lg = logit[rt];
    lg += __shfl_xor(lg, 16);
    lg += __shfl_xor(lg, 32);
    const float wexp = __expf(lg + batn);
    const int gr = rowbase + rt * 16 + colb;
    const int seg = res_index[(gr < RFn) ? gr : (RFn - 1)];
    if (lane < 16 && gr < RFn) atomicAdd(&D[seg], wexp);
    float w4[4];
    int s4[4], v4[4];
#pragma unroll
    for (int reg = 0; reg < 4; ++reg) {
      int srcl = kg * 4 + reg;
      w4[reg] = __shfl(wexp, srcl);
      s4[reg] = __shfl(seg, srcl);
      v4[reg] = (rowbase + rt * 16 + srcl) < RFn;
    }
    float s1v[4] = {0.f, 0.f, 0.f, 0.f}, s2v[4] = {0.f, 0.f, 0.f, 0.f};
#pragma unroll
    for (int c = 0; c < 8; ++c)
#pragma unroll
      for (int reg = 0; reg < 4; ++reg) {
        float t2 = acc[rt][c][reg] + bi_r[c];
        acc[rt][c][reg] = t2;
        s1v[reg] += t2;
        s2v[reg] += t2 * t2;
      }
#pragma unroll
    for (int off = 1; off <= 8; off <<= 1)
#pragma unroll
      for (int reg = 0; reg < 4; ++reg) {
        s1v[reg] += __shfl_xor(s1v[reg], off);
        s2v[reg] += __shfl_xor(s2v[reg], off);
      }
    float mu[4], rs[4];
#pragma unroll
    for (int reg = 0; reg < 4; ++reg) {
      mu[reg] = s1v[reg] * (1.0f / NFn);
      float var = s2v[reg] * (1.0f / NFn) - mu[reg] * mu[reg];
      rs[reg] = rsqrtf(var + LN_EPSn);
    }
#pragma unroll
    for (int c = 0; c < 8; ++c)
#pragma unroll
      for (int reg = 0; reg < 4; ++reg) {
        if (v4[reg]) {
          float feat = (acc[rt][c][reg] - mu[reg]) * rs[reg] * g_r[c] + be_r[c];
          atomicAdd(Nacc + (size_t)s4[reg] * NFn + c * 16 + colb, feat * w4[reg]);
        }
      }
  }
}

__global__ void div_kernel(float* __restrict__ out, const float* __restrict__ D) {
  int i = blockIdx.x * 256 + threadIdx.x;
  if (i < RAn * NFn) {
    float d = D[i >> 7];
    out[i] = (d > 0.f) ? out[i] / d : 0.f;
  }
}

extern "C" void kernel_launch(void* const* d_in, const int* in_sizes, int n_in,
                              void* d_out, int out_size, void* d_ws, size_t ws_size,
                              hipStream_t stream) {
  const float* X = (const float*)d_in[0];
  const float* Wf = (const float*)d_in[1];
  const float* bfeat = (const float*)d_in[2];
  const float* gamma = (const float*)d_in[3];
  const float* beta = (const float*)d_in[4];
  const float* Wa = (const float*)d_in[5];
  const float* ba = (const float*)d_in[6];
  const int* ri = (const int*)d_in[7];
  float* out = (float*)d_out;

  char* ws = (char*)d_ws;
  short* frag = (short*)ws;              // 65,536 B
  int* hist = (int*)(ws + 65536);        // 200,000 B
  int* T = (int*)(ws + 265536);          // 200,000 B
  int* bsum = (int*)(ws + 465536);       // 784 B
  int* boff = (int*)(ws + 466320);       // 784 B
  int* rowstart = (int*)(ws + 467104);   // 200,004 B
  int* cursor = (int*)(ws + 667108);     // 200,000 B
  int* perm = (int*)(ws + 867108);       // 2,000,000 B
  int* sseg = (int*)(ws + 2867108);      // 2,000,000 B
  const size_t NEED = 4867108ULL;        // ~4.9 MB

  prep_kernel<<<16, 256, 0, stream>>>(Wf, frag);
  hipMemsetAsync(out, 0, (size_t)RAn * NFn * sizeof(float), stream);

  if (ws_size >= NEED) {
    hipMemsetAsync(hist, 0, (size_t)RAn * sizeof(int), stream);
    hist_kernel<<<(RFn + 255) / 256, 256, 0, stream>>>(ri, hist);
    scanA_kernel<<<SCG, 256, 0, stream>>>(hist, T, bsum);
    scanB_kernel<<<1, 256, 0, stream>>>(bsum, boff);
    scanC_kernel<<<SCG, 256, 0, stream>>>(T, boff, rowstart, cursor);
    scatter_kernel<<<(RFn + 255) / 256, 256, 0, stream>>>(ri, cursor, perm, sseg);
    fused_kernel<<<NBLK2, 512, 0, stream>>>(X, frag, Wa, ba, bfeat, gamma, beta,
                                            rowstart, perm, sseg, out);
  } else {
    float* D = (float*)(ws + 65536);
    hipMemsetAsync(D, 0, (size_t)RAn * sizeof(float), stream);
    main_atomic<<<(RFn + 127) / 128, 256, 0, stream>>>(X, frag, Wa, ba, bfeat,
                                                       gamma, beta, ri, out, D);
    div_kernel<<<(RAn * NFn + 255) / 256, 256, 0, stream>>>(out, D);
  }
}

// Round 12
// 450.113 us; speedup vs baseline: 2.3772x; 2.3772x over previous
//
#include <hip/hip_runtime.h>
#include <hip/hip_bf16.h>

#define RFn 500000
#define F1n 256
#define NFn 128
#define RAn 50000
#define LN_EPSn 1e-5f
#define SPW 5                          // segments per wave (fused kernel)
#define NWV ((RAn + SPW - 1) / SPW)    // 10000 waves
#define NBLK2 ((NWV + 3) / 4)          // 2500 blocks of 4 waves
#define SCB 256
#define SCG ((RAn + SCB - 1) / SCB)    // 196

typedef float f32x4 __attribute__((ext_vector_type(4)));
typedef short short8 __attribute__((ext_vector_type(8)));

__device__ __forceinline__ short f2bf(float f) {
  __hip_bfloat16 h = __float2bfloat16(f);  // RNE
  return __builtin_bit_cast(short, h);
}

// ---------------------------------------------------------------------------
// Pack W_feat (256x128 f32) into MFMA B-frag image: frag (s,c), lane l:
// col = c*16+(l&15), k = s*32+(l>>4)*8+i  (8 bf16 per lane).
// ---------------------------------------------------------------------------
__global__ void prep_kernel(const float* __restrict__ Wf, short* __restrict__ frag) {
  int p = blockIdx.x * blockDim.x + threadIdx.x;  // 0..4095
  if (p >= 4096) return;
  int f = p >> 6, l = p & 63;
  int s = f >> 3, c = f & 7;
  int col = c * 16 + (l & 15);
  int k0 = s * 32 + ((l >> 4) << 3);
  short8 v;
#pragma unroll
  for (int i = 0; i < 8; ++i) v[i] = f2bf(Wf[(k0 + i) * NFn + col]);
  *(short8*)(frag + (size_t)p * 8) = v;
}

__global__ void hist_kernel(const int* __restrict__ ri, int* __restrict__ hist) {
  int i = blockIdx.x * 256 + threadIdx.x;
  if (i < RFn) atomicAdd(&hist[ri[i]], 1);
}

__global__ __launch_bounds__(256) void scanA_kernel(const int* __restrict__ hist,
                                                    int* __restrict__ T,
                                                    int* __restrict__ bsum) {
  __shared__ int ls[256];
  const int t = threadIdx.x, idx = blockIdx.x * 256 + t;
  const int v = (idx < RAn) ? hist[idx] : 0;
  ls[t] = v;
  __syncthreads();
  for (int off = 1; off < 256; off <<= 1) {
    int add = (t >= off) ? ls[t - off] : 0;
    __syncthreads();
    ls[t] += add;
    __syncthreads();
  }
  if (idx < RAn) T[idx] = ls[t] - v;
  if (t == 255) bsum[blockIdx.x] = ls[255];
}

__global__ __launch_bounds__(256) void scanB_kernel(int* __restrict__ bsum,
                                                    int* __restrict__ boff) {
  __shared__ int ls[256];
  const int t = threadIdx.x;
  const int v = (t < SCG) ? bsum[t] : 0;
  ls[t] = v;
  __syncthreads();
  for (int off = 1; off < 256; off <<= 1) {
    int add = (t >= off) ? ls[t - off] : 0;
    __syncthreads();
    ls[t] += add;
    __syncthreads();
  }
  if (t < SCG) boff[t] = ls[t] - v;
}

__global__ __launch_bounds__(256) void scanC_kernel(const int* __restrict__ T,
                                                    const int* __restrict__ boff,
                                                    int* __restrict__ rowstart,
                                                    int* __restrict__ cursor) {
  const int idx = blockIdx.x * 256 + threadIdx.x;
  if (idx < RAn) {
    int v = T[idx] + boff[blockIdx.x];
    rowstart[idx] = v;
    cursor[idx] = v;
  }
  if (idx == 0) rowstart[RAn] = RFn;
}

// perm[pos] = original row; sseg[pos] = its segment (segment-major order)
__global__ void scatter_kernel(const int* __restrict__ ri, int* __restrict__ cursor,
                               int* __restrict__ perm, int* __restrict__ sseg) {
  int i = blockIdx.x * 256 + threadIdx.x;
  if (i < RFn) {
    int s = ri[i];
    int pos = atomicAdd(&cursor[s], 1);
    perm[pos] = i;
    sseg[pos] = s;
  }
}

// ---------------------------------------------------------------------------
// fused: single pass, 256-thr blocks (4 waves). No LDS B-image — B-frags are
// re-read from the 64KB fragWS (L2-resident) each s-step, so occupancy is
// VGPR-bound only (~12 waves/CU). Each wave owns SPW consecutive segments =
// a contiguous range of sorted rows. Per 16-row tile: gather rows via perm,
// MFMA GEMM + in-register LN + logit/exp, then in-register segmented
// accumulation with static predicated flushes (rule #20 — no dynamic reg
// indexing anywhere). No intermediate buffer, no atomics, no spills.
// ---------------------------------------------------------------------------
__global__ __launch_bounds__(256) void fused_kernel(
    const float* __restrict__ X, const short* __restrict__ fragWS,
    const float* __restrict__ Wa, const float* __restrict__ ba,
    const float* __restrict__ bfeat, const float* __restrict__ gamma,
    const float* __restrict__ beta, const int* __restrict__ rowstart,
    const int* __restrict__ perm, const int* __restrict__ sseg,
    float* __restrict__ out) {
  __shared__ float sCoef[384];  // gamma[0:128] beta[128:256] bfeat[256:384]

  const int tid = threadIdx.x;
  if (tid < 128) {
    sCoef[tid] = gamma[tid];
    sCoef[128 + tid] = beta[tid];
    sCoef[256 + tid] = bfeat[tid];
  }
  __syncthreads();

  const int lane = tid & 63;
  const int wv = tid >> 6;
  const int colb = lane & 15;
  const int kg = lane >> 4;

  const int wgid = blockIdx.x * 4 + wv;
  const int s0 = wgid * SPW;
  if (s0 >= RAn) return;
  const int s1 = min(s0 + SPW, RAn);
  const int rbeg = rowstart[s0];
  const int rend = rowstart[s1];
  if (rend <= rbeg) return;  // all empty: out stays 0 (memset)

  const float batn = ba[0];

  // running segment state (identical on all lanes; racc[c] = col c*16+colb)
  float racc[8] = {0.f, 0.f, 0.f, 0.f, 0.f, 0.f, 0.f, 0.f};
  float wrun = 0.f;
  int curseg = -1;

  for (int base = rbeg; base < rend; base += 16) {
    const int n = min(16, rend - base);
    const int pc = base + ((colb < n) ? colb : (n - 1));
    const int row = perm[pc];
    const int seg = sseg[pc];
    const float* xp = X + (size_t)row * F1n + kg * 8;

    // -------- GEMM over K=256 (B-frags from L2-hot fragWS) --------
    f32x4 acc[8];
#pragma unroll
    for (int c = 0; c < 8; ++c) acc[c] = (f32x4)(0.0f);
    float logit = 0.f;

#pragma unroll
    for (int s = 0; s < 8; ++s) {
      short8 bfr[8];
#pragma unroll
      for (int c = 0; c < 8; ++c)
        bfr[c] = *(const short8*)(fragWS + (((s * 8 + c) * 64 + lane) * 8));
      const float4 wa0 = *(const float4*)(Wa + s * 32 + kg * 8);
      const float4 wa1 = *(const float4*)(Wa + s * 32 + kg * 8 + 4);
      const float4 x0 = *(const float4*)(xp + s * 32);
      const float4 x1 = *(const float4*)(xp + s * 32 + 4);
      float a0 = fmaxf(x0.x, 0.01f * x0.x);
      float a1 = fmaxf(x0.y, 0.01f * x0.y);
      float a2 = fmaxf(x0.z, 0.01f * x0.z);
      float a3 = fmaxf(x0.w, 0.01f * x0.w);
      float a4 = fmaxf(x1.x, 0.01f * x1.x);
      float a5 = fmaxf(x1.y, 0.01f * x1.y);
      float a6 = fmaxf(x1.z, 0.01f * x1.z);
      float a7 = fmaxf(x1.w, 0.01f * x1.w);
      logit += a0 * wa0.x + a1 * wa0.y + a2 * wa0.z + a3 * wa0.w +
               a4 * wa1.x + a5 * wa1.y + a6 * wa1.z + a7 * wa1.w;
      short8 af;
      af[0] = f2bf(a0); af[1] = f2bf(a1); af[2] = f2bf(a2); af[3] = f2bf(a3);
      af[4] = f2bf(a4); af[5] = f2bf(a5); af[6] = f2bf(a6); af[7] = f2bf(a7);
#pragma unroll
      for (int c = 0; c < 8; ++c)
        acc[c] = __builtin_amdgcn_mfma_f32_16x16x32_bf16(af, bfr[c], acc[c], 0, 0, 0);
    }

    // -------- logit -> w; LN; feat*w (in place in acc) --------
    float lg = logit;
    lg += __shfl_xor(lg, 16);
    lg += __shfl_xor(lg, 32);
    const float wexp = __expf(lg + batn);

    float w4[4];
#pragma unroll
    for (int reg = 0; reg < 4; ++reg) w4[reg] = __shfl(wexp, kg * 4 + reg);

    float s1v[4] = {0.f, 0.f, 0.f, 0.f}, s2v[4] = {0.f, 0.f, 0.f, 0.f};
#pragma unroll
    for (int c = 0; c < 8; ++c) {
      const float bi = sCoef[256 + c * 16 + colb];
#pragma unroll
      for (int reg = 0; reg < 4; ++reg) {
        float v = acc[c][reg] + bi;
        acc[c][reg] = v;
        s1v[reg] += v;
        s2v[reg] += v * v;
      }
    }
#pragma unroll
    for (int off = 1; off <= 8; off <<= 1)
#pragma unroll
      for (int reg = 0; reg < 4; ++reg) {
        s1v[reg] += __shfl_xor(s1v[reg], off);
        s2v[reg] += __shfl_xor(s2v[reg], off);
      }
    float mu[4], rs[4];
#pragma unroll
    for (int reg = 0; reg < 4; ++reg) {
      mu[reg] = s1v[reg] * (1.0f / NFn);
      const float var = s2v[reg] * (1.0f / NFn) - mu[reg] * mu[reg];
      rs[reg] = rsqrtf(var + LN_EPSn);
    }
#pragma unroll
    for (int c = 0; c < 8; ++c) {
      const float gg = sCoef[c * 16 + colb];
      const float bb = sCoef[128 + c * 16 + colb];
#pragma unroll
      for (int reg = 0; reg < 4; ++reg)
        acc[c][reg] = ((acc[c][reg] - mu[reg]) * rs[reg] * gg + bb) * w4[reg];
    }

    // -------- segmented accumulation over the n rows of this tile --------
    const int lm1 = (lane & 15) ? lane - 1 : lane;  // lane-1 within colb group
    const int segp = __shfl(seg, lm1 & 63);
    unsigned long long bm =
        __ballot(lane < n && ((lane & 15) == 0 || seg != segp));
    bm &= 0xFFFFull;

    int a = 0;
    while (a < n) {
      unsigned long long rest = (a + 1 < 16) ? (bm >> (a + 1)) : 0ull;
      const int b = rest ? (a + 1 + (int)__builtin_ctzll(rest)) : n;
      const int rseg = __shfl(seg, a);

      float ctr[8];
#pragma unroll
      for (int c = 0; c < 8; ++c) ctr[c] = 0.f;
      float wc = 0.f;
#pragma unroll
      for (int reg = 0; reg < 4; ++reg) {
        const int r = kg * 4 + reg;
        if (r >= a && r < b) {
          wc += w4[reg];
#pragma unroll
          for (int c = 0; c < 8; ++c) ctr[c] += acc[c][reg];
        }
      }
#pragma unroll
      for (int c = 0; c < 8; ++c) {
        ctr[c] += __shfl_xor(ctr[c], 16);
        ctr[c] += __shfl_xor(ctr[c], 32);
      }
      wc += __shfl_xor(wc, 16);
      wc += __shfl_xor(wc, 32);

      if (rseg != curseg) {
        if (curseg >= 0) {
          const float iw = 1.0f / wrun;
#pragma unroll
          for (int c = 0; c < 8; ++c)  // static index, predicated (rule #20)
            if ((c >> 1) == kg)
              out[(size_t)curseg * NFn + c * 16 + colb] = racc[c] * iw;
        }
        curseg = rseg;
#pragma unroll
        for (int c = 0; c < 8; ++c) racc[c] = ctr[c];
        wrun = wc;
      } else {
#pragma unroll
        for (int c = 0; c < 8; ++c) racc[c] += ctr[c];
        wrun += wc;
      }
      a = b;
    }
  }

  // final flush
  if (curseg >= 0) {
    const float iw = 1.0f / wrun;
#pragma unroll
    for (int c = 0; c < 8; ++c)  // static index, predicated (rule #20)
      if ((c >> 1) == kg)
        out[(size_t)curseg * NFn + c * 16 + colb] = racc[c] * iw;
  }
}

// ---------------------------------------------------------------------------
// Fallback path (small ws): round-1 atomic kernel, known-good.
// ---------------------------------------------------------------------------
__global__ __launch_bounds__(256) void main_atomic(
    const float* __restrict__ X, const short* __restrict__ fragWS,
    const float* __restrict__ Wa, const float* __restrict__ ba,
    const float* __restrict__ bfeat, const float* __restrict__ gamma,
    const float* __restrict__ beta, const int* __restrict__ res_index,
    float* __restrict__ Nacc, float* __restrict__ D) {
  __shared__ short sB[4096 * 8];
  const int tid = threadIdx.x;
  {
    const int4* src = (const int4*)fragWS;
    int4* dst = (int4*)sB;
#pragma unroll 4
    for (int i = tid; i < 4096; i += 256) dst[i] = src[i];
  }
  __syncthreads();
  const int lane = tid & 63;
  const int wv = tid >> 6;
  const int rowbase = blockIdx.x * 128 + wv * 32;
  const int colb = lane & 15;
  const int kg = lane >> 4;
  float g_r[8], be_r[8], bi_r[8];
#pragma unroll
  for (int c = 0; c < 8; ++c) {
    int col = c * 16 + colb;
    g_r[c] = gamma[col];
    be_r[c] = beta[col];
    bi_r[c] = bfeat[col];
  }
  const float batn = ba[0];
  f32x4 acc[2][8];
#pragma unroll
  for (int rt = 0; rt < 2; ++rt)
#pragma unroll
    for (int c = 0; c < 8; ++c) acc[rt][c] = (f32x4)(0.0f);
  float logit[2] = {0.f, 0.f};
  int gr0 = rowbase + colb;
  int gr1 = gr0 + 16;
  long r0 = (gr0 < RFn) ? gr0 : (RFn - 1);
  long r1 = (gr1 < RFn) ? gr1 : (RFn - 1);
  const float* xp0 = X + r0 * F1n + kg * 8;
  const float* xp1 = X + r1 * F1n + kg * 8;
#pragma unroll
  for (int s = 0; s < 8; ++s) {
    short8 bfr[8];
#pragma unroll
    for (int c = 0; c < 8; ++c)
      bfr[c] = *(const short8*)(sB + (((s * 8 + c) * 64 + lane) * 8));
    const float4 wa0 = *(const float4*)(Wa + s * 32 + kg * 8);
    const float4 wa1 = *(const float4*)(Wa + s * 32 + kg * 8 + 4);
#pragma unroll
    for (int rt = 0; rt < 2; ++rt) {
      const float* xp = rt ? xp1 : xp0;
      const float4 x0 = *(const float4*)(xp + s * 32);
      const float4 x1 = *(const float4*)(xp + s * 32 + 4);
      float a0 = fmaxf(x0.x, 0.01f * x0.x);
      float a1 = fmaxf(x0.y, 0.01f * x0.y);
      float a2 = fmaxf(x0.z, 0.01f * x0.z);
      float a3 = fmaxf(x0.w, 0.01f * x0.w);
      float a4 = fmaxf(x1.x, 0.01f * x1.x);
      float a5 = fmaxf(x1.y, 0.01f * x1.y);
      float a6 = fmaxf(x1.z, 0.01f * x1.z);
      float a7 = fmaxf(x1.w, 0.01f * x1.w);
      logit[rt] += a0 * wa0.x + a1 * wa0.y + a2 * wa0.z + a3 * wa0.w +
                   a4 * wa1.x + a5 * wa1.y + a6 * wa1.z + a7 * wa1.w;
      short8 af;
      af[0] = f2bf(a0); af[1] = f2bf(a1); af[2] = f2bf(a2); af[3] = f2bf(a3);
      af[4] = f2bf(a4); af[5] = f2bf(a5); af[6] = f2bf(a6); af[7] = f2bf(a7);
#pragma unroll
      for (int c = 0; c < 8; ++c)
        acc[rt][c] = __builtin_amdgcn_mfma_f32_16x16x32_bf16(af, bfr[c],
                                                             acc[rt][c], 0, 0, 0);
    }
  }
#pragma unroll
  for (int rt = 0; rt < 2; ++rt) {
    float lg = logit[rt];
    lg += __shfl_xor(lg, 16);
    lg += __shfl_xor(lg, 32);
    const float wexp = __expf(lg + batn);
    const int gr = rowbase + rt * 16 + colb;
    const int seg = res_index[(gr < RFn) ? gr : (RFn - 1)];
    if (lane < 16 && gr < RFn) atomicAdd(&D[seg], wexp);
    float w4[4];
    int s4[4], v4[4];
#pragma unroll
    for (int reg = 0; reg < 4; ++reg) {
      int srcl = kg * 4 + reg;
      w4[reg] = __shfl(wexp, srcl);
      s4[reg] = __shfl(seg, srcl);
      v4[reg] = (rowbase + rt * 16 + srcl) < RFn;
    }
    float s1v[4] = {0.f, 0.f, 0.f, 0.f}, s2v[4] = {0.f, 0.f, 0.f, 0.f};
#pragma unroll
    for (int c = 0; c < 8; ++c)
#pragma unroll
      for (int reg = 0; reg < 4; ++reg) {
        float t2 = acc[rt][c][reg] + bi_r[c];
        acc[rt][c][reg] = t2;
        s1v[reg] += t2;
        s2v[reg] += t2 * t2;
      }
#pragma unroll
    for (int off = 1; off <= 8; off <<= 1)
#pragma unroll
      for (int reg = 0; reg < 4; ++reg) {
        s1v[reg] += __shfl_xor(s1v[reg], off);
        s2v[reg] += __shfl_xor(s2v[reg], off);
      }
    float mu[4], rs[4];
#pragma unroll
    for (int reg = 0; reg < 4; ++reg) {
      mu[reg] = s1v[reg] * (1.0f / NFn);
      float var = s2v[reg] * (1.0f / NFn) - mu[reg] * mu[reg];
      rs[reg] = rsqrtf(var + LN_EPSn);
    }
#pragma unroll
    for (int c = 0; c < 8; ++c)
#pragma unroll
      for (int reg = 0; reg < 4; ++reg) {
        if (v4[reg]) {
          float feat = (acc[rt][c][reg] - mu[reg]) * rs[reg] * g_r[c] + be_r[c];
          atomicAdd(Nacc + (size_t)s4[reg] * NFn + c * 16 + colb, feat * w4[reg]);
        }
      }
  }
}

__global__ void div_kernel(float* __restrict__ out, const float* __restrict__ D) {
  int i = blockIdx.x * 256 + threadIdx.x;
  if (i < RAn * NFn) {
    float d = D[i >> 7];
    out[i] = (d > 0.f) ? out[i] / d : 0.f;
  }
}

extern "C" void kernel_launch(void* const* d_in, const int* in_sizes, int n_in,
                              void* d_out, int out_size, void* d_ws, size_t ws_size,
                              hipStream_t stream) {
  const float* X = (const float*)d_in[0];
  const float* Wf = (const float*)d_in[1];
  const float* bfeat = (const float*)d_in[2];
  const float* gamma = (const float*)d_in[3];
  const float* beta = (const float*)d_in[4];
  const float* Wa = (const float*)d_in[5];
  const float* ba = (const float*)d_in[6];
  const int* ri = (const int*)d_in[7];
  float* out = (float*)d_out;

  char* ws = (char*)d_ws;
  short* frag = (short*)ws;              // 65,536 B
  int* hist = (int*)(ws + 65536);        // 200,000 B
  int* T = (int*)(ws + 265536);          // 200,000 B
  int* bsum = (int*)(ws + 465536);       // 784 B
  int* boff = (int*)(ws + 466320);       // 784 B
  int* rowstart = (int*)(ws + 467104);   // 200,004 B
  int* cursor = (int*)(ws + 667108);     // 200,000 B
  int* perm = (int*)(ws + 867108);       // 2,000,000 B
  int* sseg = (int*)(ws + 2867108);      // 2,000,000 B
  const size_t NEED = 4867108ULL;        // ~4.9 MB

  prep_kernel<<<16, 256, 0, stream>>>(Wf, frag);
  hipMemsetAsync(out, 0, (size_t)RAn * NFn * sizeof(float), stream);

  if (ws_size >= NEED) {
    hipMemsetAsync(hist, 0, (size_t)RAn * sizeof(int), stream);
    hist_kernel<<<(RFn + 255) / 256, 256, 0, stream>>>(ri, hist);
    scanA_kernel<<<SCG, 256, 0, stream>>>(hist, T, bsum);
    scanB_kernel<<<1, 256, 0, stream>>>(bsum, boff);
    scanC_kernel<<<SCG, 256, 0, stream>>>(T, boff, rowstart, cursor);
    scatter_kernel<<<(RFn + 255) / 256, 256, 0, stream>>>(ri, cursor, perm, sseg);
    fused_kernel<<<NBLK2, 256, 0, stream>>>(X, frag, Wa, ba, bfeat, gamma, beta,
                                            rowstart, perm, sseg, out);
  } else {
    float* D = (float*)(ws + 65536);
    hipMemsetAsync(D, 0, (size_t)RAn * sizeof(float), stream);
    main_atomic<<<(RFn + 127) / 128, 256, 0, stream>>>(X, frag, Wa, ba, bfeat,
                                                       gamma, beta, ri, out, D);
    div_kernel<<<(RAn * NFn + 255) / 256, 256, 0, stream>>>(out, D);
  }
}